// Round 1
// baseline (442.490 us; speedup 1.0000x reference)
//
#include <hip/hip_runtime.h>

// Causal depthwise conv1d: x(b=8, l=4096, d=2048) fp32, W(d,1,k=4), bias(d).
// y[b,l,d] = sum_j W[d,0,j] * x[b, l-3+j, d] + bias[d]   (x[l<0] = 0)
//
// Memory-bound: 256 MiB in + 256 MiB out => floor ~81us @ 6.3 TB/s.
// Strategy: float4 along d (innermost, coalesced); per-thread sliding window
// along l so x is read exactly once. Grid 1024x256 (16 waves/CU).

#define CC_B 8
#define CC_L 4096
#define CC_D 2048
#define CC_D4 (CC_D / 4)      // 512 float4 lanes per row
#define CC_LCHUNK 64
#define CC_NCHUNK (CC_L / CC_LCHUNK)

__global__ __launch_bounds__(256) void CausalConv_85521388798425_kernel(
    const float* __restrict__ x,
    const float* __restrict__ W,
    const float* __restrict__ bias,
    float* __restrict__ out)
{
    const int t = blockIdx.x * blockDim.x + threadIdx.x;

    const int d4   = t % CC_D4;          // float4 lane along d (consecutive threads -> coalesced)
    const int rest = t / CC_D4;
    const int lc   = rest % CC_NCHUNK;   // which l-chunk
    const int b    = rest / CC_NCHUNK;   // batch
    const int l0   = lc * CC_LCHUNK;

    // Weights: W[(d4*4+i)*4 + j] -> load 4x4 block as 4 float4, transpose so
    // wj holds W[.][j] across the 4 d-components.
    const float4* Wv = reinterpret_cast<const float4*>(W + (size_t)d4 * 16);
    const float4 wr0 = Wv[0];
    const float4 wr1 = Wv[1];
    const float4 wr2 = Wv[2];
    const float4 wr3 = Wv[3];
    const float4 w0 = make_float4(wr0.x, wr1.x, wr2.x, wr3.x);
    const float4 w1 = make_float4(wr0.y, wr1.y, wr2.y, wr3.y);
    const float4 w2 = make_float4(wr0.z, wr1.z, wr2.z, wr3.z);
    const float4 w3 = make_float4(wr0.w, wr1.w, wr2.w, wr3.w);
    const float4 bv = reinterpret_cast<const float4*>(bias)[d4];

    const float4* __restrict__ xrow =
        reinterpret_cast<const float4*>(x) + (size_t)b * CC_L * CC_D4 + d4;
    float4* __restrict__ orow =
        reinterpret_cast<float4*>(out) + (size_t)b * CC_L * CC_D4 + d4;

    // Sliding window: xm3 = x[l-3], xm2 = x[l-2], xm1 = x[l-1]
    float4 xm3 = make_float4(0.f, 0.f, 0.f, 0.f);
    float4 xm2 = xm3;
    float4 xm1 = xm3;
    if (l0 > 0) {  // halo (l0 >= 64 here, so all three are valid)
        xm3 = xrow[(size_t)(l0 - 3) * CC_D4];
        xm2 = xrow[(size_t)(l0 - 2) * CC_D4];
        xm1 = xrow[(size_t)(l0 - 1) * CC_D4];
    }

    #pragma unroll 8
    for (int l = l0; l < l0 + CC_LCHUNK; ++l) {
        const float4 x0 = xrow[(size_t)l * CC_D4];
        float4 o;
        o.x = fmaf(w0.x, xm3.x, fmaf(w1.x, xm2.x, fmaf(w2.x, xm1.x, fmaf(w3.x, x0.x, bv.x))));
        o.y = fmaf(w0.y, xm3.y, fmaf(w1.y, xm2.y, fmaf(w2.y, xm1.y, fmaf(w3.y, x0.y, bv.y))));
        o.z = fmaf(w0.z, xm3.z, fmaf(w1.z, xm2.z, fmaf(w2.z, xm1.z, fmaf(w3.z, x0.z, bv.z))));
        o.w = fmaf(w0.w, xm3.w, fmaf(w1.w, xm2.w, fmaf(w2.w, xm1.w, fmaf(w3.w, x0.w, bv.w))));
        orow[(size_t)l * CC_D4] = o;
        xm3 = xm2; xm2 = xm1; xm1 = x0;
    }
}

extern "C" void kernel_launch(void* const* d_in, const int* in_sizes, int n_in,
                              void* d_out, int out_size, void* d_ws, size_t ws_size,
                              hipStream_t stream) {
    const float* x    = (const float*)d_in[0];
    const float* W    = (const float*)d_in[1];
    const float* bias = (const float*)d_in[2];
    float* out        = (float*)d_out;

    const int total_threads = CC_B * CC_NCHUNK * CC_D4;  // 8 * 64 * 512 = 262144
    const int block = 256;
    const int grid  = total_threads / block;             // 1024
    CausalConv_85521388798425_kernel<<<grid, block, 0, stream>>>(x, W, bias, out);
}